// Round 7
// baseline (215.555 us; speedup 1.0000x reference)
//
#include <hip/hip_runtime.h>
#include <math.h>

// Dims: B=2, H=256, W=256, C=64, heads=8, dh=64, hd=512, dim_out=64.
// Inputs fp32, output fp32 (proven r1/r2). Internals bf16 + MFMA.
//
// attn[b,h,i,j] = (Wk_i^T G[b] Wq_j)/(||k_i|| ||q_j||)*rescale[h],
// G[b] = Xd^T Xd (Gram of 2x2-avg-pooled input).
// out = x@W_eff[b] + bproj + dwconv2(gelu(dwconv1(x@W_pos + bc1d)))
// W_eff[b] = Wv @ blockdiag_h(attn_h^T) @ Wproj,  W_pos = Wv @ Wc1d.
//
// r7: single x-pass kernel (xb + Gram + pmain-MFMA fused; x read once),
// attention chain fully in-LDS (T/nq/nk never hit HBM). 5 launches.

typedef unsigned short u16;
typedef unsigned int u32;
typedef __attribute__((ext_vector_type(8))) short short8;
typedef __attribute__((ext_vector_type(4))) float f32x4;

__device__ __forceinline__ float bf2f(u16 h) { return __uint_as_float(((u32)h) << 16); }
__device__ __forceinline__ u16 f2bf(float f) {
    u32 u = __float_as_uint(f);
    return (u16)((u + 0x7fffu + ((u >> 16) & 1u)) >> 16);
}
__device__ __forceinline__ float rbf(float f) { return bf2f(f2bf(f)); }
__device__ __forceinline__ u32 pk2(float lo, float hi) {
    return (u32)f2bf(lo) | ((u32)f2bf(hi) << 16);
}
__device__ __forceinline__ void unpack8(uint4 v, float* f) {
    u32 a[4] = {v.x, v.y, v.z, v.w};
#pragma unroll
    for (int i = 0; i < 4; ++i) {
        f[2 * i]     = __uint_as_float(a[i] << 16);
        f[2 * i + 1] = __uint_as_float(a[i] & 0xffff0000u);
    }
}
__device__ __forceinline__ float gelu_exact(float v) {
    return 0.5f * v * (1.f + erff(v * 0.70710678118654752f));
}

// ---------------------------------------------------------------------------
// K1: blocks 0..322 weight fp32->bf16; 323..338 Wpos = Wv@Wc1d.
__global__ __launch_bounds__(256) void k_wfront(
    const float* __restrict__ wq_f, const float* __restrict__ wk_f,
    const float* __restrict__ wv_f, const float* __restrict__ rs_f,
    const float* __restrict__ wp_f, const float* __restrict__ bp_f,
    const float* __restrict__ wc_f, const float* __restrict__ bc_f,
    const float* __restrict__ p1_f, const float* __restrict__ p2_f,
    u32* __restrict__ wb32, float* __restrict__ Wpos) {
    int blk = blockIdx.x;
    int t = threadIdx.x;
    if (blk < 323) {
        u32 pid = (u32)blk * 256u + t;
        if (pid < 82564u) {
            const float* src; u32 p;
            if      (pid < 16384u) { src = wq_f; p = pid; }
            else if (pid < 32768u) { src = wk_f; p = pid - 16384u; }
            else if (pid < 49152u) { src = wv_f; p = pid - 32768u; }
            else if (pid < 49156u) { src = rs_f; p = pid - 49152u; }
            else if (pid < 65540u) { src = wp_f; p = pid - 49156u; }
            else if (pid < 65572u) { src = bp_f; p = pid - 65540u; }
            else if (pid < 81956u) { src = wc_f; p = pid - 65572u; }
            else if (pid < 81988u) { src = bc_f; p = pid - 81956u; }
            else if (pid < 82276u) { src = p1_f; p = pid - 81988u; }
            else                   { src = p2_f; p = pid - 82276u; }
            wb32[pid] = (u32)f2bf(src[2 * p]) | ((u32)f2bf(src[2 * p + 1]) << 16);
        }
    } else {
        int wpid = (blk - 323) * 256 + t;     // 0..4095
        int o = wpid & 63, c = wpid >> 6;
        float s = 0.f;
        for (int k = 0; k < 512; ++k)
            s += rbf(wv_f[c * 512 + k]) * rbf(wc_f[k * 64 + o]);
        Wpos[c * 64 + o] = s;
    }
}

// ---------------------------------------------------------------------------
// K2: fused x-pass. 512 blocks = (b, row-pair, col-half): 2 rows x 128 cols
// = 256 px each. Reads fp32 x ONCE; emits xb (bf16), pooled Gram partial
// (64 tokens), and pbuf = xb@Wpos + bc1d via MFMA from LDS-resident bf16.
__global__ __launch_bounds__(256) void k_xpass(
    const float* __restrict__ x, const float* __restrict__ Wpos,
    const u16* __restrict__ bc1d, u16* __restrict__ xb,
    float* __restrict__ partials, u16* __restrict__ pbuf) {
    __shared__ u16 xbs[256 * 72];            // bf16 pixels (px stride 72 u16)
    __shared__ float xvs[64 * 68];           // pooled tokens fp32
    int blk = blockIdx.x, t = threadIdx.x;
    int b = blk >> 8, yp = (blk >> 1) & 127, xh = blk & 1;
    int lane = t & 63, wv = t >> 6, col = lane & 15, quad = lane >> 4;

    // B-frags (Wpos) + bias — global loads issued up front
    short8 bfr[2][4];
#pragma unroll
    for (int kh = 0; kh < 2; ++kh)
#pragma unroll
        for (int nt = 0; nt < 4; ++nt) {
            short8 v;
#pragma unroll
            for (int j = 0; j < 8; ++j)
                v[j] = (short)f2bf(Wpos[(kh * 32 + quad * 8 + j) * 64 + nt * 16 + col]);
            bfr[kh][nt] = v;
        }
    float bias[4];
#pragma unroll
    for (int nt = 0; nt < 4; ++nt) bias[nt] = bf2f(bc1d[nt * 16 + col]);

    // phase 1: load x, write xb(global)+xbs(LDS), pooled sums -> xvs
    const size_t row0 = ((size_t)(b * 256 + 2 * yp)) * 256 + (size_t)xh * 128;
#pragma unroll
    for (int i2 = 0; i2 < 4; ++i2) {
        int item = t + 256 * i2;              // 0..1023
        int pt = item >> 4, cq = item & 15;   // pooled col 0..63, ch-quad
        size_t o0 = (row0 + 2 * pt) * 64 + cq * 4;
        float4 a0 = *(const float4*)(x + o0);
        float4 a1 = *(const float4*)(x + o0 + 64);
        float4 a2 = *(const float4*)(x + o0 + 16384);
        float4 a3 = *(const float4*)(x + o0 + 16384 + 64);
        uint2 u0 = make_uint2(pk2(a0.x, a0.y), pk2(a0.z, a0.w));
        uint2 u1 = make_uint2(pk2(a1.x, a1.y), pk2(a1.z, a1.w));
        uint2 u2 = make_uint2(pk2(a2.x, a2.y), pk2(a2.z, a2.w));
        uint2 u3 = make_uint2(pk2(a3.x, a3.y), pk2(a3.z, a3.w));
        *(uint2*)(xb + o0)              = u0;
        *(uint2*)(xb + o0 + 64)         = u1;
        *(uint2*)(xb + o0 + 16384)      = u2;
        *(uint2*)(xb + o0 + 16384 + 64) = u3;
        int p00 = 2 * pt, p10 = 128 + 2 * pt;
        *(uint2*)(&xbs[p00 * 72 + cq * 4])       = u0;
        *(uint2*)(&xbs[(p00 + 1) * 72 + cq * 4]) = u1;
        *(uint2*)(&xbs[p10 * 72 + cq * 4])       = u2;
        *(uint2*)(&xbs[(p10 + 1) * 72 + cq * 4]) = u3;
        float4 s;
        s.x = 0.25f * (a0.x + a1.x + a2.x + a3.x);
        s.y = 0.25f * (a0.y + a1.y + a2.y + a3.y);
        s.z = 0.25f * (a0.z + a1.z + a2.z + a3.z);
        s.w = 0.25f * (a0.w + a1.w + a2.w + a3.w);
        *(float4*)(&xvs[pt * 68 + cq * 4]) = s;
    }
    __syncthreads();

    // Gram over 64 pooled tokens
    {
        int r0 = (t >> 4) << 2, c0 = (t & 15) << 2;
        float acc[4][4] = {{0.f}};
        for (int tok = 0; tok < 64; ++tok) {
            float4 av = *(const float4*)(&xvs[tok * 68 + r0]);
            float4 bv = *(const float4*)(&xvs[tok * 68 + c0]);
            float ar[4] = {av.x, av.y, av.z, av.w};
            float br[4] = {bv.x, bv.y, bv.z, bv.w};
#pragma unroll
            for (int i = 0; i < 4; ++i)
#pragma unroll
                for (int j = 0; j < 4; ++j)
                    acc[i][j] += ar[i] * br[j];
        }
        float* outp = partials + (size_t)blk * 4096;
#pragma unroll
        for (int i = 0; i < 4; ++i)
            *(float4*)(&outp[(r0 + i) * 64 + c0]) =
                make_float4(acc[i][0], acc[i][1], acc[i][2], acc[i][3]);
    }

    // pmain MFMA: A-frags from LDS xbs
    f32x4 acc[4][4];
#pragma unroll
    for (int g = 0; g < 4; ++g) {
        int P0 = wv * 64 + g * 16;
        short8 a0 = *(const short8*)(&xbs[(P0 + col) * 72 + quad * 8]);
        short8 a1 = *(const short8*)(&xbs[(P0 + col) * 72 + 32 + quad * 8]);
#pragma unroll
        for (int nt = 0; nt < 4; ++nt) {
            f32x4 z = {0.f, 0.f, 0.f, 0.f};
            z = __builtin_amdgcn_mfma_f32_16x16x32_bf16(a0, bfr[0][nt], z, 0, 0, 0);
            z = __builtin_amdgcn_mfma_f32_16x16x32_bf16(a1, bfr[1][nt], z, 0, 0, 0);
            acc[g][nt] = z;
        }
    }
    __syncthreads();                         // all xbs reads done; reuse for out
#pragma unroll
    for (int g = 0; g < 4; ++g) {
        int P0 = wv * 64 + g * 16;
#pragma unroll
        for (int nt = 0; nt < 4; ++nt)
#pragma unroll
            for (int r = 0; r < 4; ++r)
                xbs[(P0 + quad * 4 + r) * 72 + nt * 16 + col] =
                    f2bf(acc[g][nt][r] + bias[nt]);
    }
    __syncthreads();
#pragma unroll
    for (int k = 0; k < 8; ++k) {
        int linear = k * 256 + t;
        int px = linear >> 3, oct = linear & 7;
        uint4 v = *(const uint4*)(&xbs[px * 72 + oct * 8]);
        int r = px >> 7, cl = px & 127;
        size_t gp = row0 + (size_t)r * 256 + cl;
        *(uint4*)(pbuf + gp * 64 + oct * 8) = v;
    }
}

// ---------------------------------------------------------------------------
// K3: blocks 0..63 reduce 512 partials -> G[2][4096] (+zero Weff);
//     64..1087 conv1 (tbuf = gelu(dwconv3x3(pbuf, Wpe1))).
__global__ __launch_bounds__(256) void k_mid(
    const float* __restrict__ partials, float* __restrict__ G, float* __restrict__ Weff,
    const u16* __restrict__ pbuf, const u16* __restrict__ wpe1, u16* __restrict__ tbuf) {
    __shared__ __align__(16) char shm[29376];
    int blk = blockIdx.x, t = threadIdx.x;
    if (blk < 64) {
        float* red = (float*)shm;
        if (t < 128) Weff[blk * 128 + t] = 0.f;
        int e = blk * 128 + (t & 127);        // 0..8191 flat over G
        int b = e >> 12, e4 = e & 4095;
        int half = t >> 7;
        float s = 0.f;
        for (int pp = 0; pp < 128; ++pp)
            s += partials[((size_t)(b * 256 + half * 128 + pp)) * 4096 + e4];
        red[t] = s;
        __syncthreads();
        if (t < 128) G[e] = red[t] + red[t + 128];
        return;
    }
    // conv1, cb = blk - 64
    u16* sm = (u16*)shm;
    int cb = blk - 64;
    int b  = cb >> 9;
    int ty = (cb >> 3) & 63;
    int tx = cb & 7;
    int gy0 = ty * 4, gx0 = tx * 32;

    for (int i = t; i < 1632; i += 256) {
        int px = i >> 3, ch = i & 7;
        int hy = px / 34, hx = px - hy * 34;
        int gy = gy0 + hy - 1, gx = gx0 + hx - 1;
        uint4 v = make_uint4(0, 0, 0, 0);
        if ((unsigned)gy < 256u && (unsigned)gx < 256u)
            v = *(const uint4*)(pbuf + ((size_t)((b << 16) + (gy << 8) + gx)) * 64 + ch * 8);
        *(uint4*)(&sm[px * 72 + ch * 8]) = v;
    }
    int oct = t & 7;
    float w[8][9];
#pragma unroll
    for (int j = 0; j < 8; ++j)
#pragma unroll
        for (int k = 0; k < 9; ++k) w[j][k] = bf2f(wpe1[(oct * 8 + j) * 9 + k]);
    __syncthreads();

#pragma unroll
    for (int s = 0; s < 4; ++s) {
        int lp = (t >> 3) + s * 32;
        int ly = lp >> 5, lx = lp & 31;
        float acc[8] = {0.f, 0.f, 0.f, 0.f, 0.f, 0.f, 0.f, 0.f};
#pragma unroll
        for (int dy = 0; dy < 3; ++dy)
#pragma unroll
            for (int dx = 0; dx < 3; ++dx) {
                int hp = (ly + dy) * 34 + lx + dx;
                uint4 v = *(const uint4*)(&sm[hp * 72 + oct * 8]);
                float f[8];
                unpack8(v, f);
                int tap = dy * 3 + dx;
#pragma unroll
                for (int j = 0; j < 8; ++j) acc[j] += f[j] * w[j][tap];
            }
        u32 pk[4];
#pragma unroll
        for (int q = 0; q < 4; ++q)
            pk[q] = pk2(gelu_exact(acc[2 * q]), gelu_exact(acc[2 * q + 1]));
        size_t gpix = (size_t)(b << 16) + ((size_t)(gy0 + ly) << 8) + gx0 + lx;
        *(uint4*)(tbuf + gpix * 64 + oct * 8) = make_uint4(pk[0], pk[1], pk[2], pk[3]);
    }
}

// ---------------------------------------------------------------------------
// K4: whole attention chain per (b,h): G -> T/U -> norms -> logits/softmax
// -> P -> Weff partial (atomicAdd). 16 blocks. T/nq/nk stay in LDS.
__global__ __launch_bounds__(256) void k_attn_chain(
    const float* __restrict__ G,
    const u16* __restrict__ wqb, const u16* __restrict__ wkb,
    const u16* __restrict__ wvb, const u16* __restrict__ wpb,
    const u16* __restrict__ rsb, float* __restrict__ Weff) {
    __shared__ __align__(16) float A[64 * 68];    // products -> attns
    __shared__ __align__(16) float Bv[64 * 68];   // G -> Ts -> Pls
    __shared__ __align__(16) u16 Wks[64 * 72];    // Wk -> Wv
    __shared__ __align__(16) u16 Wpj[64 * 72];    // Wq -> Wproj
    __shared__ float nqa[64], nka[64];
    int blk = blockIdx.x, t = threadIdx.x;
    int b = blk >> 3, h = blk & 7;
    int c = t >> 2, q = t & 3, j0 = q * 16;

    // 1. loads: G -> Bv, Wq -> Wpj, Wk -> Wks
#pragma unroll
    for (int i = 0; i < 4; ++i) {
        int idx = i * 256 + t;                // float4 idx 0..1023
        int row = idx >> 4, c4 = (idx & 15) * 4;
        *(float4*)(&Bv[row * 68 + c4]) = *(const float4*)(&G[b * 4096 + row * 64 + c4]);
    }
    *(short8*)(&Wpj[c * 72 + j0])     = *(const short8*)(&wqb[c * 512 + h * 64 + j0]);
    *(short8*)(&Wpj[c * 72 + j0 + 8]) = *(const short8*)(&wqb[c * 512 + h * 64 + j0 + 8]);
    *(short8*)(&Wks[c * 72 + j0])     = *(const short8*)(&wkb[c * 512 + h * 64 + j0]);
    *(short8*)(&Wks[c * 72 + j0 + 8]) = *(const short8*)(&wkb[c * 512 + h * 64 + j0 + 8]);
    __syncthreads();

    // 2. Tr = (G@Wq)[c][j0..j0+16), Ur = (G@Wk)[c][...]
    float Tr[16], Ur[16];
#pragma unroll
    for (int jj = 0; jj < 16; ++jj) { Tr[jj] = 0.f; Ur[jj] = 0.f; }
    for (int k = 0; k < 64; ++k) {
        float g = Bv[c * 68 + k];
        short8 q0 = *(const short8*)(&Wpj[k * 72 + j0]);
        short8 q1 = *(const short8*)(&Wpj[k * 72 + j0 + 8]);
        short8 k0 = *(const short8*)(&Wks[k * 72 + j0]);
        short8 k1 = *(const short8*)(&Wks[k * 72 + j0 + 8]);
#pragma unroll
        for (int jj = 0; jj < 8; ++jj) {
            Tr[jj]     += g * bf2f((u16)q0[jj]);
            Tr[8 + jj] += g * bf2f((u16)q1[jj]);
            Ur[jj]     += g * bf2f((u16)k0[jj]);
            Ur[8 + jj] += g * bf2f((u16)k1[jj]);
        }
    }
    __syncthreads();

    // 3. nq
    {
        short8 w0 = *(const short8*)(&Wpj[c * 72 + j0]);
        short8 w1 = *(const short8*)(&Wpj[c * 72 + j0 + 8]);
#pragma unroll
        for (int jj = 0; jj < 8; ++jj) {
            A[c * 68 + j0 + jj]     = bf2f((u16)w0[jj]) * Tr[jj];
            A[c * 68 + j0 + 8 + jj] = bf2f((u16)w1[jj]) * Tr[8 + jj];
        }
    }
    __syncthreads();
    if (t < 64) {
        float s = 0.f;
        for (int cc = 0; cc < 64; ++cc) s += A[cc * 68 + t];
        nqa[t] = fmaxf(sqrtf(fmaxf(s, 0.f)), 1e-12f);
    }
    __syncthreads();
    // 4. nk
    {
        short8 w0 = *(const short8*)(&Wks[c * 72 + j0]);
        short8 w1 = *(const short8*)(&Wks[c * 72 + j0 + 8]);
#pragma unroll
        for (int jj = 0; jj < 8; ++jj) {
            A[c * 68 + j0 + jj]     = bf2f((u16)w0[jj]) * Ur[jj];
            A[c * 68 + j0 + 8 + jj] = bf2f((u16)w1[jj]) * Ur[8 + jj];
        }
    }
    __syncthreads();
    if (t < 64) {
        float s = 0.f;
        for (int cc = 0; cc < 64; ++cc) s += A[cc * 68 + t];
        nka[t] = fmaxf(sqrtf(fmaxf(s, 0.f)), 1e-12f);
    }
    __syncthreads();

    // 5. Ts -> Bv (over G, dead); Wproj -> Wpj (over Wq, dead)
#pragma unroll
    for (int q2 = 0; q2 < 4; ++q2)
        *(float4*)(&Bv[c * 68 + j0 + 4 * q2]) =
            make_float4(Tr[4 * q2], Tr[4 * q2 + 1], Tr[4 * q2 + 2], Tr[4 * q2 + 3]);
    *(short8*)(&Wpj[c * 72 + j0])     = *(const short8*)(&wpb[(h * 64 + c) * 64 + j0]);
    *(short8*)(&Wpj[c * 72 + j0 + 8]) = *(const short8*)(&wpb[(h * 64 + c) * 64 + j0 + 8]);
    __syncthreads();

    // 6. logits + softmax -> A
    {
        int i = c;
        float L[16];
#pragma unroll
        for (int jj = 0; jj < 16; ++jj) L[jj] = 0.f;
        for (int cc = 0; cc < 64; ++cc) {
            float wk = bf2f(Wks[cc * 72 + i]);
#pragma unroll
            for (int q2 = 0; q2 < 4; ++q2) {
                float4 tv = *(const float4*)(&Bv[cc * 68 + j0 + 4 * q2]);
                L[4 * q2 + 0] += wk * tv.x;
                L[4 * q2 + 1] += wk * tv.y;
                L[4 * q2 + 2] += wk * tv.z;
                L[4 * q2 + 3] += wk * tv.w;
            }
        }
        float rs = bf2f(rsb[h]);
        float nki = nka[i];
        float m = -1e30f;
#pragma unroll
        for (int jj = 0; jj < 16; ++jj) {
            L[jj] = L[jj] * rs / (nki * nqa[j0 + jj]);
            m = fmaxf(m, L[jj]);
        }
        m = fmaxf(m, __shfl_xor(m, 1));
        m = fmaxf(m, __shfl_xor(m, 2));
        float s = 0.f;
#pragma unroll
        for (int jj = 0; jj < 16; ++jj) {
            L[jj] = __expf(L[jj] - m);
            s += L[jj];
        }
        s += __shfl_xor(s, 1);
        s += __shfl_xor(s, 2);
        float inv = 1.f / s;
#pragma unroll
        for (int q2 = 0; q2 < 4; ++q2)
            *(float4*)(&A[i * 68 + j0 + 4 * q2]) =
                make_float4(L[4 * q2] * inv, L[4 * q2 + 1] * inv,
                            L[4 * q2 + 2] * inv, L[4 * q2 + 3] * inv);
    }
    __syncthreads();

    // 7. Wv -> Wks (over Wk, dead); P = attn^T @ Wproj -> Bv (over Ts, dead)
    {
        *(short8*)(&Wks[c * 72 + j0])     = *(const short8*)(&wvb[c * 512 + h * 64 + j0]);
        *(short8*)(&Wks[c * 72 + j0 + 8]) = *(const short8*)(&wvb[c * 512 + h * 64 + j0 + 8]);
        int j = c, oq = q;
        float Pl[16];
#pragma unroll
        for (int jj = 0; jj < 16; ++jj) Pl[jj] = 0.f;
        for (int i2 = 0; i2 < 64; ++i2) {
            float a = A[i2 * 68 + j];
            short8 w0 = *(const short8*)(&Wpj[i2 * 72 + oq * 16]);
            short8 w1 = *(const short8*)(&Wpj[i2 * 72 + oq * 16 + 8]);
#pragma unroll
            for (int jj = 0; jj < 8; ++jj) {
                Pl[jj]     += a * bf2f((u16)w0[jj]);
                Pl[8 + jj] += a * bf2f((u16)w1[jj]);
            }
        }
#pragma unroll
        for (int q2 = 0; q2 < 4; ++q2)
            *(float4*)(&Bv[j * 68 + oq * 16 + 4 * q2]) =
                make_float4(Pl[4 * q2], Pl[4 * q2 + 1], Pl[4 * q2 + 2], Pl[4 * q2 + 3]);
    }
    __syncthreads();

    // 8. Weff partial: Wv_h @ P -> atomicAdd
    {
        int oq = q;
        float acc[16];
#pragma unroll
        for (int jj = 0; jj < 16; ++jj) acc[jj] = 0.f;
        for (int j2 = 0; j2 < 64; ++j2) {
            float wv = bf2f(Wks[c * 72 + j2]);
#pragma unroll
            for (int q2 = 0; q2 < 4; ++q2) {
                float4 pv = *(const float4*)(&Bv[j2 * 68 + oq * 16 + 4 * q2]);
                acc[4 * q2 + 0] += wv * pv.x;
                acc[4 * q2 + 1] += wv * pv.y;
                acc[4 * q2 + 2] += wv * pv.z;
                acc[4 * q2 + 3] += wv * pv.w;
            }
        }
        float* W = Weff + b * 4096 + c * 64 + oq * 16;
#pragma unroll
        for (int jj = 0; jj < 16; ++jj) atomicAdd(&W[jj], acc[jj]);
    }
}

// ---------------------------------------------------------------------------
// K5: out = xb @ Weff[b] + bproj + dwconv3x3(tbuf, Wpe2) (r6 body, 35 KB LDS)
__global__ __launch_bounds__(256) void k_final(const u16* __restrict__ xb,
                                               const u16* __restrict__ tbuf,
                                               const float* __restrict__ Weff,
                                               const u16* __restrict__ wpe2,
                                               const u16* __restrict__ bproj,
                                               float* __restrict__ out) {
    __shared__ __align__(16) char shm[34816];
    u16* sm = (u16*)shm;
    float* stage = (float*)shm;
    int t = threadIdx.x;
    int blk = blockIdx.x;
    int b  = blk >> 9;
    int ty = (blk >> 3) & 63;
    int tx = blk & 7;
    int gy0 = ty * 4, gx0 = tx * 32;

    for (int i = t; i < 1632; i += 256) {
        int px = i >> 3, ch = i & 7;
        int hy = px / 34, hx = px - hy * 34;
        int gy = gy0 + hy - 1, gx = gx0 + hx - 1;
        uint4 v = make_uint4(0, 0, 0, 0);
        if ((unsigned)gy < 256u && (unsigned)gx < 256u)
            v = *(const uint4*)(tbuf + ((size_t)((b << 16) + (gy << 8) + gx)) * 64 + ch * 8);
        *(uint4*)(&sm[px * 72 + ch * 8]) = v;
    }
    int oct = t & 7;
    float cacc[4][8];
    {
        float w[8][9];
#pragma unroll
        for (int j = 0; j < 8; ++j)
#pragma unroll
            for (int k = 0; k < 9; ++k) w[j][k] = bf2f(wpe2[(oct * 8 + j) * 9 + k]);
        __syncthreads();
#pragma unroll
        for (int s = 0; s < 4; ++s) {
            int lp = (t >> 3) + s * 32;
            int ly = lp >> 5, lx = lp & 31;
#pragma unroll
            for (int j = 0; j < 8; ++j) cacc[s][j] = 0.f;
#pragma unroll
            for (int dy = 0; dy < 3; ++dy)
#pragma unroll
                for (int dx = 0; dx < 3; ++dx) {
                    int hp = (ly + dy) * 34 + lx + dx;
                    uint4 v = *(const uint4*)(&sm[hp * 72 + oct * 8]);
                    float f[8];
                    unpack8(v, f);
                    int tap = dy * 3 + dx;
#pragma unroll
                    for (int j = 0; j < 8; ++j) cacc[s][j] += f[j] * w[j][tap];
                }
        }
    }
    __syncthreads();
#pragma unroll
    for (int s = 0; s < 4; ++s) {
        int lp = (t >> 3) + s * 32;
#pragma unroll
        for (int j = 0; j < 8; ++j)
            stage[lp * 68 + oct * 8 + j] = cacc[s][j];
    }

    int lane = t & 63, wv = t >> 6;
    int col = lane & 15, quad = lane >> 4;
    const float* W = Weff + b * 4096;
    short8 bfr[2][4];
#pragma unroll
    for (int kh = 0; kh < 2; ++kh)
#pragma unroll
        for (int nt = 0; nt < 4; ++nt) {
            short8 v;
#pragma unroll
            for (int j = 0; j < 8; ++j)
                v[j] = (short)f2bf(W[(kh * 32 + quad * 8 + j) * 64 + nt * 16 + col]);
            bfr[kh][nt] = v;
        }
    float bias[4];
#pragma unroll
    for (int nt = 0; nt < 4; ++nt) bias[nt] = bf2f(bproj[nt * 16 + col]);
    __syncthreads();

#pragma unroll
    for (int g = 0; g < 2; ++g) {
        int grp = wv * 2 + g;
        int ly = grp >> 1;
        int lxb = (grp & 1) * 16;
        size_t rowpix = (size_t)(b << 16) + ((size_t)(gy0 + ly) << 8) + gx0;
        const short8* ap = (const short8*)(xb + (rowpix + lxb + col) * 64);
        short8 a0 = ap[quad];
        short8 a1 = ap[4 + quad];
#pragma unroll
        for (int nt = 0; nt < 4; ++nt) {
            f32x4 acc = {0.f, 0.f, 0.f, 0.f};
            acc = __builtin_amdgcn_mfma_f32_16x16x32_bf16(a0, bfr[0][nt], acc, 0, 0, 0);
            acc = __builtin_amdgcn_mfma_f32_16x16x32_bf16(a1, bfr[1][nt], acc, 0, 0, 0);
#pragma unroll
            for (int r = 0; r < 4; ++r) {
                int lp = ly * 32 + lxb + quad * 4 + r;
                stage[lp * 68 + nt * 16 + col] += acc[r] + bias[nt];
            }
        }
    }
    __syncthreads();

#pragma unroll
    for (int k = 0; k < 8; ++k) {
        int linear = k * 256 + t;
        int px = linear >> 4, c4 = linear & 15;
        int ly = px >> 5, lx = px & 31;
        float4 v = *(const float4*)(&stage[px * 68 + c4 * 4]);
        size_t gpix = (size_t)(b << 16) + ((size_t)(gy0 + ly) << 8) + gx0 + lx;
        *(float4*)(out + gpix * 64 + c4 * 4) = v;
    }
}

// ---------------------------------------------------------------------------
extern "C" void kernel_launch(void* const* d_in, const int* in_sizes, int n_in,
                              void* d_out, int out_size, void* d_ws, size_t ws_size,
                              hipStream_t stream) {
    const float* x = (const float*)d_in[0];
    float* out = (float*)d_out;

    char* w = (char*)d_ws;
    size_t off = 0;
    auto alloc = [&](size_t bytes) -> void* {
        void* p = w + off;
        off += (bytes + 255) & ~(size_t)255;
        return p;
    };
    u16* xb = (u16*)alloc((size_t)16777216 * 2);
    u16* wb = (u16*)alloc((size_t)165128 * 2);
    u16* wqb = wb;
    u16* wkb = wqb + 32768;
    u16* wvb = wkb + 32768;
    u16* rsb = wvb + 32768;
    u16* wpb = rsb + 8;
    u16* bpb = wpb + 32768;
    u16* wcb = bpb + 64;
    u16* bcb = wcb + 32768;
    u16* p1b = bcb + 64;
    u16* p2b = p1b + 576;
    (void)wcb;

    float* partials = (float*)alloc((size_t)512 * 4096 * 4);
    float* G        = (float*)alloc((size_t)2 * 4096 * 4);
    float* Weff     = (float*)alloc((size_t)2 * 4096 * 4);
    float* Wpos     = (float*)alloc((size_t)4096 * 4);
    u16*   pbuf     = (u16*)alloc((size_t)2 * 65536 * 64 * 2);
    u16*   tbuf     = (u16*)alloc((size_t)2 * 65536 * 64 * 2);

    hipLaunchKernelGGL(k_wfront, dim3(339), dim3(256), 0, stream,
                       (const float*)d_in[1], (const float*)d_in[2], (const float*)d_in[3],
                       (const float*)d_in[4], (const float*)d_in[5], (const float*)d_in[6],
                       (const float*)d_in[7], (const float*)d_in[8], (const float*)d_in[9],
                       (const float*)d_in[10],
                       (u32*)wb, Wpos);
    hipLaunchKernelGGL(k_xpass, dim3(512), dim3(256), 0, stream,
                       x, Wpos, bcb, xb, partials, pbuf);
    hipLaunchKernelGGL(k_mid, dim3(1088), dim3(256), 0, stream,
                       partials, G, Weff, pbuf, p1b, tbuf);
    hipLaunchKernelGGL(k_attn_chain, dim3(16), dim3(256), 0, stream,
                       G, wqb, wkb, wvb, wpb, rsb, Weff);
    hipLaunchKernelGGL(k_final, dim3(1024), dim3(256), 0, stream,
                       xb, tbuf, Weff, p2b, bpb, out);
}